// Round 3
// baseline (23952.333 us; speedup 1.0000x reference)
//
#include <hip/hip_runtime.h>

// VQ nearest-codebook argmin — numpy-fp32 semantics emulation.
//
// Evidence (rounds 1+2): two independent exact-fp64 kernels both gave
// absmax 855 -> the np reference is fp32. Its argmin is decided by fp32
// quantization of d = (s1 - 2G) + s2 at ulp(256)=3.05e-5 with first-index
// tie-break. We reproduce:
//   s1 = numpy pairwise fp32 sum of fl32(z_i^2)   (bit-exact order)
//   s2 = numpy pairwise fp32 sum of fl32(e_i^2)   (bit-exact order)
//   G  = z.e in fp64 -> correctly-rounded fp32 2G (BLAS differs by ~ulp(G);
//        flip prob through the 3e-5 quantizer ~0.1 rows total, accepted)
//   d  = fl32(fl32(s1 - 2G) + s2); argmin, ties -> lowest index.

#define DDIM 256
#define KCODES 1024

// numpy pairwise_sum for one 128-element block of squares, exact order:
// r[j] = a[j]*a[j]; 15x { r[j] += a[i+j]*a[i+j] }; ((r0+r1)+(r2+r3))+((r4+r5)+(r6+r7))
// Fused with the fp64 dot accumulation against zz[].
__device__ __forceinline__ float block128_sq_dot(
    const float* __restrict__ a, const float* __restrict__ zz, double& dot)
{
#pragma clang fp contract(off)
    float r[8];
    #pragma unroll
    for (int j = 0; j < 8; ++j) {
        float v = a[j];
        float sq = v * v;          // one rounding per square (matches flat*flat temp)
        r[j] = sq;
        dot = fma((double)zz[j], (double)v, dot);
    }
    #pragma unroll
    for (int i = 8; i < 128; i += 8) {
        #pragma unroll
        for (int j = 0; j < 8; ++j) {
            float v = a[i + j];
            float sq = v * v;
            r[j] = r[j] + sq;      // fp32 add, numpy accumulator order
            dot = fma((double)zz[i + j], (double)v, dot);
        }
    }
    return ((r[0] + r[1]) + (r[2] + r[3])) + ((r[4] + r[5]) + (r[6] + r[7]));
}

// numpy pairwise fp32 sum of squares for 128 elements (no dot) — for s1.
__device__ __forceinline__ float block128_sq(const float* __restrict__ a)
{
#pragma clang fp contract(off)
    float r[8];
    #pragma unroll
    for (int j = 0; j < 8; ++j) { float v = a[j]; r[j] = v * v; }
    #pragma unroll
    for (int i = 8; i < 128; i += 8) {
        #pragma unroll
        for (int j = 0; j < 8; ++j) { float v = a[i + j]; r[j] = r[j] + v * v; }
    }
    return ((r[0] + r[1]) + (r[2] + r[3])) + ((r[4] + r[5]) + (r[6] + r[7]));
}

__global__ __launch_bounds__(256) void vq_argmin_np32(
    const float* __restrict__ z, const float* __restrict__ emb,
    int* __restrict__ out, int N)
{
#pragma clang fp contract(off)
    __shared__ float zrow[4][DDIM];

    const int wic  = threadIdx.x >> 6;
    const int lane = threadIdx.x & 63;
    const int row  = blockIdx.x * 4 + wic;
    const bool valid = (row < N);

    if (valid) {
        for (int d = lane; d < DDIM; d += 64)
            zrow[wic][d] = z[(size_t)row * DDIM + d];
    }
    __syncthreads();
    if (!valid) return;

    const float* zr = zrow[wic];

    // s1 = numpy pairwise fp32 sum of z_i^2 over 256 = pw(0:128) + pw(128:256)
    const float s1 = block128_sq(zr) + block128_sq(zr + 128);

    float bestv = 3.4e38f;
    int   bestk = 0;

    for (int kk = 0; kk < KCODES / 64; ++kk) {       // 16 codes per lane
        const int k = kk * 64 + lane;
        const float* __restrict__ e = emb + (size_t)k * DDIM;

        double dot = 0.0;
        float b0 = block128_sq_dot(e,       zr,       dot);
        float b1 = block128_sq_dot(e + 128, zr + 128, dot);
        float s2 = b0 + b1;                           // pairwise top combine

        float twog = 2.0f * (float)dot;               // fl32(2G), x2 exact
        float t1   = s1 - twog;                       // fp32 rounding step 1
        float d    = t1 + s2;                         // fp32 rounding step 2

        if (d < bestv || (d == bestv && k < bestk)) { bestv = d; bestk = k; }
    }

    // wave-wide min-reduce, lowest index on exact fp32 tie (numpy argmin semantics)
    #pragma unroll
    for (int off = 1; off < 64; off <<= 1) {
        float ov = __shfl_xor(bestv, off, 64);
        int   ok = __shfl_xor(bestk, off, 64);
        if (ov < bestv || (ov == bestv && ok < bestk)) { bestv = ov; bestk = ok; }
    }

    if (lane == 0) out[row] = bestk;
}

extern "C" void kernel_launch(void* const* d_in, const int* in_sizes, int n_in,
                              void* d_out, int out_size, void* d_ws, size_t ws_size,
                              hipStream_t stream) {
    const float* z   = (const float*)d_in[0];
    const float* emb = (const float*)d_in[1];
    int* out = (int*)d_out;
    const int N = in_sizes[0] / DDIM;              // 32768 rows
    const int grid = (N + 3) / 4;                  // 4 rows (1 wave each) per block
    vq_argmin_np32<<<dim3(grid), dim3(256), 0, stream>>>(z, emb, out, N);
}

// Round 4
// 491.039 us; speedup vs baseline: 48.7789x; 48.7789x over previous
//
#include <hip/hip_runtime.h>

// VQ nearest-codebook argmin — numpy-fp32 semantics (validated round 3) on a
// tiled fp64-GEMM engine (validated round 1).
//
// LOCKED numerics (absmax 0 in round 3):
//   s1 = numpy pairwise fp32 sum of fl32(z_i^2)
//   s2 = numpy pairwise fp32 sum of fl32(e_i^2)   (hoisted: row-independent)
//   G  = z.e accumulated in fp64 (order-free: 1e-16 perturbation is
//        invisible through the fp32 quantizer), 2G = 2.0f*(float)G
//   d  = fl32(fl32(s1 - 2G) + s2), argmin with first-index tie-break.

#define DDIM 256
#define KCODES 1024
#define BM 64
#define BN 64
#define BK 32
#define STA 260   // A LDS stride: float4-aligned stores, 2-way-free reads
#define STB 33    // B LDS stride: 2-way-free reads

// numpy pairwise fp32 sum of squares over 128 contiguous elements.
__device__ __forceinline__ float block128_sq(const float* __restrict__ a)
{
#pragma clang fp contract(off)
    float r[8];
    #pragma unroll
    for (int j = 0; j < 8; ++j) { float v = a[j]; r[j] = v * v; }
    #pragma unroll
    for (int i = 8; i < 128; i += 8) {
        #pragma unroll
        for (int j = 0; j < 8; ++j) { float v = a[i + j]; r[j] = r[j] + v * v; }
    }
    return ((r[0] + r[1]) + (r[2] + r[3])) + ((r[4] + r[5]) + (r[6] + r[7]));
}

__global__ __launch_bounds__(256) void vq_s2_kernel(
    const float* __restrict__ emb, float* __restrict__ s2)
{
    const int k = blockIdx.x * 256 + threadIdx.x;
    if (k < KCODES) {
        const float* e = emb + (size_t)k * DDIM;
        s2[k] = block128_sq(e) + block128_sq(e + 128);
    }
}

__global__ __launch_bounds__(256, 2) void vq_argmin_main(
    const float* __restrict__ z, const float* __restrict__ emb,
    const float* __restrict__ s2g, int* __restrict__ out, int N)
{
#pragma clang fp contract(off)
    __shared__ float As[BM * STA];    // 66560 B
    __shared__ float Bs[BN * STB];    //  8448 B
    __shared__ float s2s[KCODES];     //  4096 B
    __shared__ float s1s[BM];         //   256 B  (total 79360 B -> 2 blocks/CU)

    const int tid  = threadIdx.x;
    const int row0 = blockIdx.x * BM;

    for (int c = tid; c < KCODES; c += 256) s2s[c] = s2g[c];

    // stage A panel (64 rows x 256), coalesced float4
    #pragma unroll
    for (int i = 0; i < 16; ++i) {
        int f4 = i * 256 + tid;
        int r  = f4 >> 6, c4 = f4 & 63;
        int rg = row0 + r; if (rg > N - 1) rg = N - 1;
        *reinterpret_cast<float4*>(&As[r * STA + c4 * 4]) =
            *reinterpret_cast<const float4*>(z + (size_t)rg * DDIM + c4 * 4);
    }
    __syncthreads();

    // per-row s1 (bit-exact numpy pairwise, from the staged copy)
    if (tid < BM) {
        const float* ar = &As[tid * STA];
        s1s[tid] = block128_sq(ar) + block128_sq(ar + 128);
    }
    // (first __syncthreads inside the ks loop orders s1s/As before use)

    const int tr = tid >> 4;   // 0..15 -> rows  tr*4..tr*4+3
    const int tc = tid & 15;   // 0..15 -> codes tc*4..tc*4+3

    float bestv[4];
    int   bestk[4];
    #pragma unroll
    for (int j = 0; j < 4; ++j) { bestv[j] = 3.4e38f; bestk[j] = 0; }

    for (int ct = 0; ct < KCODES / BN; ++ct) {
        double acc[4][4];
        #pragma unroll
        for (int j = 0; j < 4; ++j)
            #pragma unroll
            for (int i = 0; i < 4; ++i) acc[j][i] = 0.0;

        for (int ks = 0; ks < DDIM / BK; ++ks) {
            __syncthreads();                       // prev Bs reads done
            #pragma unroll
            for (int i = 0; i < 2; ++i) {          // stage B tile [code][kk]
                int f4 = i * 256 + tid;
                int c  = f4 >> 3, k4 = f4 & 7;
                float4 v = *reinterpret_cast<const float4*>(
                    emb + (size_t)(ct * BN + c) * DDIM + ks * BK + k4 * 4);
                float* bp = &Bs[c * STB + k4 * 4];
                bp[0] = v.x; bp[1] = v.y; bp[2] = v.z; bp[3] = v.w;
            }
            __syncthreads();

            #pragma unroll
            for (int kk = 0; kk < BK; ++kk) {
                double a[4], b[4];
                #pragma unroll
                for (int j = 0; j < 4; ++j)
                    a[j] = (double)As[(tr * 4 + j) * STA + ks * BK + kk];
                #pragma unroll
                for (int i = 0; i < 4; ++i)
                    b[i] = (double)Bs[(tc * 4 + i) * STB + kk];
                #pragma unroll
                for (int j = 0; j < 4; ++j)
                    #pragma unroll
                    for (int i = 0; i < 4; ++i)
                        acc[j][i] = fma(a[j], b[i], acc[j][i]);
            }
        }

        // epilogue: locked fp32 recipe, first-index tie-break (codes ascend)
        #pragma unroll
        for (int i = 0; i < 4; ++i) {
            const int   c   = ct * BN + tc * 4 + i;
            const float s2v = s2s[c];
            #pragma unroll
            for (int j = 0; j < 4; ++j) {
                float twog = 2.0f * (float)acc[j][i];   // exact x2 of rounded G
                float t1   = s1s[tr * 4 + j] - twog;    // fp32 rounding 1
                float dv   = t1 + s2v;                  // fp32 rounding 2
                if (dv < bestv[j] || (dv == bestv[j] && c < bestk[j])) {
                    bestv[j] = dv; bestk[j] = c;
                }
            }
        }
    }

    // reduce across the 16 tc lanes (xor 1,2,4,8 keeps tr fixed)
    #pragma unroll
    for (int off = 1; off < 16; off <<= 1) {
        #pragma unroll
        for (int j = 0; j < 4; ++j) {
            float ov = __shfl_xor(bestv[j], off, 64);
            int   ok = __shfl_xor(bestk[j], off, 64);
            if (ov < bestv[j] || (ov == bestv[j] && ok < bestk[j])) {
                bestv[j] = ov; bestk[j] = ok;
            }
        }
    }

    if (tc == 0) {
        #pragma unroll
        for (int j = 0; j < 4; ++j) {
            int r = row0 + tr * 4 + j;
            if (r < N) out[r] = bestk[j];
        }
    }
}

extern "C" void kernel_launch(void* const* d_in, const int* in_sizes, int n_in,
                              void* d_out, int out_size, void* d_ws, size_t ws_size,
                              hipStream_t stream) {
    const float* z   = (const float*)d_in[0];
    const float* emb = (const float*)d_in[1];
    int*   out = (int*)d_out;
    float* s2  = (float*)d_ws;                    // 1024 floats scratch
    const int N = in_sizes[0] / DDIM;             // 32768
    vq_s2_kernel<<<dim3((KCODES + 255) / 256), dim3(256), 0, stream>>>(emb, s2);
    vq_argmin_main<<<dim3((N + BM - 1) / BM), dim3(256), 0, stream>>>(z, emb, s2, out, N);
}